// Round 2
// baseline (2091.988 us; speedup 1.0000x reference)
//
#include <hip/hip_runtime.h>
#include <hip/hip_bf16.h>

#define DE 100
#define RK 40
#define NENT 10000
#define BATCH 128
#define KDIM 1600          // 40*40
#define MN 10000           // 100*100
#define PRED_SIZE (BATCH*NENT)

typedef __bf16 bf16x8 __attribute__((ext_vector_type(8)));
typedef float floatx4 __attribute__((ext_vector_type(4)));

// RTNE float -> bf16 bits
static __device__ __forceinline__ unsigned short f2bf(float f) {
    unsigned int u = __builtin_bit_cast(unsigned int, f);
    unsigned int lsb = (u >> 16) & 1u;
    u += 0x7fffu + lsb;
    return (unsigned short)(u >> 16);
}

// ---------------- prep_A: A'[m=(i,j)][e=(a*40+c)] = sum_b f0[a,i,b] f1[b,j,c] ----------------
__global__ void prep_A_kernel(const float* __restrict__ f0, const float* __restrict__ f1,
                              unsigned short* __restrict__ Abf) {
    const int m = blockIdx.x;          // i*100 + j
    const int i = m / 100, j = m % 100;
    const int t = threadIdx.x;
    __shared__ __align__(16) float P[KDIM];  // F0[a*40+b]
    __shared__ __align__(16) float Q[KDIM];  // F1[b*40+c]
    for (int e = t; e < KDIM; e += 256) {
        const int u = e / 40, v = e % 40;
        P[e] = f0[u*4000 + i*40 + v];
        Q[e] = f1[u*4000 + j*40 + v];
    }
    __syncthreads();
    for (int o = t; o < 400; o += 256) {
        const int x  = o / 10;          // a
        const int z4 = (o % 10) * 4;    // c base
        float a0=0.f, a1=0.f, a2=0.f, a3=0.f;
        #pragma unroll
        for (int y = 0; y < 40; ++y) {
            const float s = P[x*40 + y];
            const float4 q = *reinterpret_cast<const float4*>(&Q[y*40 + z4]);
            a0 += s*q.x; a1 += s*q.y; a2 += s*q.z; a3 += s*q.w;
        }
        ushort4 r;
        r.x = f2bf(a0); r.y = f2bf(a1); r.z = f2bf(a2); r.w = f2bf(a3);
        *reinterpret_cast<ushort4*>(&Abf[(size_t)m*KDIM + x*40 + z4]) = r;
    }
}

// ---------------- prep_B: B'[n=(k,l)][e=(a*40+c)] = sum_d f2[c,k,d] f3[d,l,a] ----------------
__global__ void prep_B_kernel(const float* __restrict__ f2, const float* __restrict__ f3,
                              unsigned short* __restrict__ Bbf) {
    const int n = blockIdx.x;          // k*100 + l
    const int k = n / 100, l = n % 100;
    const int t = threadIdx.x;
    __shared__ __align__(16) float P[KDIM];   // F2[c*40+d]
    __shared__ __align__(16) float Q[KDIM];   // F3[d*40+a]
    __shared__ __align__(16) float Rt[KDIM];  // R[c*40+a]
    for (int e = t; e < KDIM; e += 256) {
        const int u = e / 40, v = e % 40;
        P[e] = f2[u*4000 + k*40 + v];
        Q[e] = f3[u*4000 + l*40 + v];
    }
    __syncthreads();
    for (int o = t; o < 400; o += 256) {
        const int x  = o / 10;          // c
        const int z4 = (o % 10) * 4;    // a base
        float a0=0.f, a1=0.f, a2=0.f, a3=0.f;
        #pragma unroll
        for (int y = 0; y < 40; ++y) {
            const float s = P[x*40 + y];
            const float4 q = *reinterpret_cast<const float4*>(&Q[y*40 + z4]);
            a0 += s*q.x; a1 += s*q.y; a2 += s*q.z; a3 += s*q.w;
        }
        Rt[x*40 + z4 + 0] = a0; Rt[x*40 + z4 + 1] = a1;
        Rt[x*40 + z4 + 2] = a2; Rt[x*40 + z4 + 3] = a3;
    }
    __syncthreads();
    for (int o = t; o < 400; o += 256) {
        const int a  = o / 10;
        const int c4 = (o % 10) * 4;
        ushort4 r;
        r.x = f2bf(Rt[(c4+0)*40 + a]);
        r.y = f2bf(Rt[(c4+1)*40 + a]);
        r.z = f2bf(Rt[(c4+2)*40 + a]);
        r.w = f2bf(Rt[(c4+3)*40 + a]);
        *reinterpret_cast<ushort4*>(&Bbf[(size_t)n*KDIM + a*40 + c4]) = r;
    }
}

// ---------------- GEMM: W[m][n] = sum_e A'[m][e] * B'[n][e] ----------------
// 256x256 tile, BK=64, 8 waves (2M x 4N). 4 phases per K-tile (m201 8-phase
// template): per phase {ds_read subtile || stage issue -> barrier -> lgkm(0)
// -> setprio(1) 16 MFMA setprio(0) -> barrier}. Staggered staging:
// A(kt+1)->buf^1 at phases 0-1; B(kt+2)->cur buf B-region (dead after phase 0)
// at phases 2-3. Counted vmcnt(4) once per K-tile (never 0 in main loop).
typedef __attribute__((address_space(1))) void gvoid;
typedef __attribute__((address_space(3))) void lvoid;
static __device__ __forceinline__ void async_cp16(const void* g, void* l) {
    gvoid* gp = (gvoid*)(unsigned long long)g;
    lvoid* lp = (lvoid*)(unsigned int)(unsigned long long)l;
    __builtin_amdgcn_global_load_lds(gp, lp, 16, 0, 0);
}

#define NKT 25            // 1600 / 64 K-tiles

__global__ __launch_bounds__(512, 2) void gemm_kernel(const unsigned short* __restrict__ A,
                                                      const unsigned short* __restrict__ Bm,
                                                      float* __restrict__ W) {
    extern __shared__ unsigned short lds[];   // buf0: A@0 B@16384 ; buf1: A@32768 B@49152
    const int t = threadIdx.x;
    const int w = t >> 6, l = t & 63;
    const int wm = w >> 2, wn = w & 3;        // 2 x 4 wave grid
    const int quad = l >> 4, lrow = l & 15;
    const int swz = lrow & 7;

    // XCD-aware bijective swizzle: 1600 blocks, 8 XCDs, 200 per XCD
    const int orig = blockIdx.x;
    const int sb = (orig & 7) * 200 + (orig >> 3);
    const int by = sb / 40, bx = sb % 40;
    const int m0 = by * 256, n0 = bx * 256;

    // staging: thread t stages row i*64 + (t>>3), LDS chunk t&7, source chunk swizzled
    const int srow = t >> 3;
    const int schk = (t & 7) ^ (srow & 7);
    const unsigned short* gA[4];
    const unsigned short* gB[4];
    #pragma unroll
    for (int i = 0; i < 4; ++i) {
        int ra = m0 + i*64 + srow; if (ra > MN-1) ra = MN-1;
        int rb = n0 + i*64 + srow; if (rb > MN-1) rb = MN-1;
        gA[i] = A  + (size_t)ra*KDIM + schk*8;
        gB[i] = Bm + (size_t)rb*KDIM + schk*8;
    }
    const int ldst = t * 8;   // per-thread LDS ushort offset within a 64-row region

    // hoisted LDS read base pointers (immediate offsets do the rest)
    const int ch0  = (quad ^ swz) * 8;          // kk=0 chunk ushort-offset
    const int ch1  = ch0 ^ 32;                  // kk=1 (bit2 of chunk -> +64B)
    const int aRow = (wm*128 + lrow) * 64;
    const int bRow = (wn*64  + lrow) * 64;
    const unsigned short* pAk0[2] = { lds +         aRow + ch0, lds + 32768 + aRow + ch0 };
    const unsigned short* pAk1[2] = { lds +         aRow + ch1, lds + 32768 + aRow + ch1 };
    const unsigned short* pBk0[2] = { lds + 16384 + bRow + ch0, lds + 49152 + bRow + ch0 };
    const unsigned short* pBk1[2] = { lds + 16384 + bRow + ch1, lds + 49152 + bRow + ch1 };

    floatx4 acc[8][4] = {};
    bf16x8 bfr[4][2], afr[2][2];
    int kA = 64, kB = 128;   // ushort k-offsets for A(kt+1), B(kt+2)

#define RD_B(c)  do { _Pragma("unroll") for (int ni = 0; ni < 4; ++ni) {              \
        bfr[ni][0] = *reinterpret_cast<const bf16x8*>(pBk0[c] + ni*1024);             \
        bfr[ni][1] = *reinterpret_cast<const bf16x8*>(pBk1[c] + ni*1024); } } while(0)

#define RD_A(c,p) do { _Pragma("unroll") for (int j = 0; j < 2; ++j) {                \
        afr[j][0] = *reinterpret_cast<const bf16x8*>(pAk0[c] + (2*(p)+j)*1024);       \
        afr[j][1] = *reinterpret_cast<const bf16x8*>(pAk1[c] + (2*(p)+j)*1024); } } while(0)

#define STG_A(c,i0) do { unsigned short* d = lds + (((c)^1)*32768) + (i0)*4096 + ldst; \
        async_cp16(gA[(i0)]   + kA, d);                                                \
        async_cp16(gA[(i0)+1] + kA, d + 4096); } while(0)

#define STG_B(c,i0) do { unsigned short* d = lds + ((c)*32768) + 16384 + (i0)*4096 + ldst; \
        async_cp16(gB[(i0)]   + kB, d);                                                \
        async_cp16(gB[(i0)+1] + kB, d + 4096); } while(0)

#define BARO() do { __builtin_amdgcn_s_barrier();                                      \
        asm volatile("s_waitcnt lgkmcnt(0)" ::: "memory");                             \
        __builtin_amdgcn_sched_barrier(0); } while(0)

#define MM(p) do { __builtin_amdgcn_s_setprio(1);                                      \
        _Pragma("unroll") for (int j = 0; j < 2; ++j)                                  \
        _Pragma("unroll") for (int ni = 0; ni < 4; ++ni) {                             \
            acc[2*(p)+j][ni] = __builtin_amdgcn_mfma_f32_16x16x32_bf16(                \
                afr[j][0], bfr[ni][0], acc[2*(p)+j][ni], 0, 0, 0);                     \
            acc[2*(p)+j][ni] = __builtin_amdgcn_mfma_f32_16x16x32_bf16(                \
                afr[j][1], bfr[ni][1], acc[2*(p)+j][ni], 0, 0, 0); }                   \
        __builtin_amdgcn_s_setprio(0); } while(0)

#define VMW(n) asm volatile("s_waitcnt vmcnt(" #n ")" ::: "memory")

#define TILE(c, AOK, BOK, VMT) do {                                                    \
        RD_B(c); RD_A(c,0); if (AOK) { STG_A(c,0); }                                   \
        BARO(); MM(0); __builtin_amdgcn_s_barrier();                                   \
        RD_A(c,1); if (AOK) { STG_A(c,2); }                                            \
        BARO(); MM(1); __builtin_amdgcn_s_barrier();                                   \
        RD_A(c,2); if (BOK) { STG_B(c,0); }                                            \
        BARO(); MM(2); __builtin_amdgcn_s_barrier();                                   \
        RD_A(c,3); if (BOK) { STG_B(c,2); }                                            \
        BARO(); MM(3);                                                                 \
        VMT;                                                                           \
        __builtin_amdgcn_s_barrier();                                                  \
    } while (0)

    // prologue: A0,B0 -> buf0; B1 -> buf1 B-region (12 loads/thread)
    #pragma unroll
    for (int i = 0; i < 4; ++i) async_cp16(gA[i],      lds +          i*4096 + ldst);
    #pragma unroll
    for (int i = 0; i < 4; ++i) async_cp16(gB[i],      lds + 16384 +  i*4096 + ldst);
    #pragma unroll
    for (int i = 0; i < 4; ++i) async_cp16(gB[i] + 64, lds + 49152 +  i*4096 + ldst);
    VMW(4);                       // A0,B0 resident; B1 may be in flight
    __builtin_amdgcn_s_barrier();

    for (int it = 0; it < 12; ++it) {
        TILE(0, true, true, VMW(4));
        kA += 64; kB += 64;
        if (it < 11) { TILE(1, true, true,  VMW(4)); }
        else         { TILE(1, true, false, VMW(0)); }    // kt=23: only A(24) pending
        kA += 64; kB += 64;
    }
    TILE(0, false, false, ((void)0));                      // kt=24

#undef RD_B
#undef RD_A
#undef STG_A
#undef STG_B
#undef BARO
#undef MM
#undef VMW
#undef TILE

    #pragma unroll
    for (int mi = 0; mi < 8; ++mi) {
        #pragma unroll
        for (int ni = 0; ni < 4; ++ni) {
            #pragma unroll
            for (int reg = 0; reg < 4; ++reg) {
                const int rg = m0 + wm*128 + mi*16 + quad*4 + reg;
                const int cg = n0 + wn*64 + ni*16 + lrow;
                if (rg < MN && cg < MN)
                    W[(size_t)rg * MN + cg] = acc[mi][ni][reg];
            }
        }
    }
}

// ---------------- fused BatchNorm1d x3 (training-mode batch stats), gather ----------------
__global__ void bn3_kernel(const float* __restrict__ E, const float* __restrict__ Rw,
                           const int* __restrict__ r_idx, const int* __restrict__ e_idx1,
                           const int* __restrict__ e_idx2,
                           const float* __restrict__ bnrg, const float* __restrict__ bnrb,
                           const float* __restrict__ bneg, const float* __restrict__ bneb,
                           float* __restrict__ rbn, float* __restrict__ e1bn,
                           float* __restrict__ e2bn) {
    const int grp = blockIdx.x / DE;
    const int f   = blockIdx.x % DE;
    const int b   = threadIdx.x;
    const float* src  = (grp == 0) ? Rw   : E;
    const int*   idx  = (grp == 0) ? r_idx : (grp == 1 ? e_idx1 : e_idx2);
    const float* gam  = (grp == 0) ? bnrg : bneg;
    const float* bet  = (grp == 0) ? bnrb : bneb;
    float* out        = (grp == 0) ? rbn  : (grp == 1 ? e1bn : e2bn);
    __shared__ float red[BATCH];
    const int row = idx[b];
    const float x = src[row*DE + f];
    red[b] = x; __syncthreads();
    for (int s = 64; s > 0; s >>= 1) { if (b < s) red[b] += red[b + s]; __syncthreads(); }
    const float mu = red[0] * (1.0f/BATCH);
    __syncthreads();
    const float d = x - mu;
    red[b] = d * d; __syncthreads();
    for (int s = 64; s > 0; s >>= 1) { if (b < s) red[b] += red[b + s]; __syncthreads(); }
    const float var = red[0] * (1.0f/BATCH);
    out[b*DE + f] = gam[f] * d / sqrtf(var + 1e-5f) + bet[f];
}

// ---------------- single BatchNorm (for W_out), no gather ----------------
__global__ void bn_kernel(const float* __restrict__ src,
                          const float* __restrict__ gamma, const float* __restrict__ beta,
                          float* __restrict__ out) {
    const int f = blockIdx.x;
    const int b = threadIdx.x;
    __shared__ float red[BATCH];
    const float x = src[b*DE + f];
    red[b] = x; __syncthreads();
    for (int s = 64; s > 0; s >>= 1) { if (b < s) red[b] += red[b + s]; __syncthreads(); }
    const float mu = red[0] * (1.0f/BATCH);
    __syncthreads();
    const float d = x - mu;
    red[b] = d * d; __syncthreads();
    for (int s = 64; s > 0; s >>= 1) { if (b < s) red[b] += red[b + s]; __syncthreads(); }
    const float var = red[0] * (1.0f/BATCH);
    out[b*DE + f] = gamma[f] * d / sqrtf(var + 1e-5f) + beta[f];
}

// ---------------- proj stage 1: factor-shared batched contraction ----------------
// out[fi][b][u*40+v] = sum_p vec_fi[b][p] * fac_fi[u*4000 + p*40 + v]
// grid: 3 factors x 40 u x 4 batch-groups = 480 blocks
__global__ void proj_stage1(const float* __restrict__ rb, const float* __restrict__ e1b,
                            const float* __restrict__ e2b,
                            const float* __restrict__ f0, const float* __restrict__ f1,
                            const float* __restrict__ f3,
                            float* __restrict__ outg) {
    const int bi = blockIdx.x;
    const int fi = bi / 160, rest = bi % 160;
    const int u = rest / 4, b0 = (rest % 4) * 32;
    const float* vec = (fi == 0) ? rb : (fi == 1 ? e1b : e2b);
    const float* fac = (fi == 0) ? f0 : (fi == 1 ? f1 : f3);
    float* og = outg + (size_t)fi * (BATCH*KDIM);
    __shared__ __align__(16) float F[4000];   // F[p*40+v]
    __shared__ __align__(16) float V[3200];   // V[bb*100+p]
    const int t = threadIdx.x;
    for (int e = t; e < 4000; e += 256) F[e] = fac[u*4000 + e];
    for (int e = t; e < 3200; e += 256) V[e] = vec[b0*100 + e];
    __syncthreads();
    #pragma unroll
    for (int it = 0; it < 5; ++it) {
        const int o = t + it*256;
        const int bb = o / 40, v = o % 40;
        const float* Vb = &V[bb*100];
        float acc = 0.f;
        #pragma unroll 4
        for (int p = 0; p < 100; ++p) acc += Vb[p] * F[p*40 + v];
        og[(size_t)(b0+bb)*KDIM + u*40 + v] = acc;
    }
}

// ---------------- proj stages 2-4: per-batch small contractions in LDS ----------------
__global__ void proj_stage2(const float* __restrict__ Rg, const float* __restrict__ f2,
                            float* __restrict__ wraw) {
    const int b = blockIdx.x, t = threadIdx.x;
    __shared__ float R0[KDIM], E1[KDIM], E2[KDIM], T[KDIM], S[KDIM];
    const float* R0g = Rg + (size_t)b*KDIM;
    const float* E1g = Rg + (size_t)BATCH*KDIM   + (size_t)b*KDIM;
    const float* E2g = Rg + (size_t)2*BATCH*KDIM + (size_t)b*KDIM;
    for (int e = t; e < KDIM; e += 256) { R0[e] = R0g[e]; E1[e] = E1g[e]; E2[e] = E2g[e]; }
    __syncthreads();
    // T[a,c] = sum_be R0[a,be] E1[be,c]
    for (int e = t; e < KDIM; e += 256) {
        const int a = e / 40, c = e % 40;
        float acc = 0.f;
        #pragma unroll
        for (int y = 0; y < 40; ++y) acc += R0[a*40+y] * E1[y*40+c];
        T[e] = acc;
    }
    __syncthreads();
    // S[c,d] = sum_a T[a,c] E2[d,a]
    for (int e = t; e < KDIM; e += 256) {
        const int c = e / 40, d = e % 40;
        float acc = 0.f;
        #pragma unroll
        for (int y = 0; y < 40; ++y) acc += T[y*40+c] * E2[d*40+y];
        S[e] = acc;
    }
    __syncthreads();
    // wraw[b,j] = sum_{c,d} S[c,d] f2[c,j,d]
    if (t < DE) {
        float acc = 0.f;
        for (int c = 0; c < 40; ++c) {
            #pragma unroll
            for (int d = 0; d < 40; ++d)
                acc += S[c*40+d] * f2[c*4000 + t*40 + d];
        }
        wraw[b*DE + t] = acc;
    }
}

// ---------------- scores: out[b][n] = dot(wbn[b], E[n]) ----------
__global__ void scores_kernel(const float* __restrict__ wbn, const float* __restrict__ E,
                              float* __restrict__ scores) {
    const int bx = blockIdx.x;
    const int b = bx >> 3, chunk = bx & 7;
    const int t = threadIdx.x;
    __shared__ __align__(16) float wsh[DE];
    if (t < DE) wsh[t] = wbn[b*DE + t];
    __syncthreads();
    const float4* wv = reinterpret_cast<const float4*>(wsh);
    const int n_end = (chunk + 1) * 1250;
    for (int n = chunk*1250 + t; n < n_end; n += 256) {
        const float4* er = reinterpret_cast<const float4*>(E + (size_t)n * DE);
        float acc = 0.f;
        #pragma unroll
        for (int q = 0; q < 25; ++q) {
            const float4 e4 = er[q], w4 = wv[q];
            acc += e4.x*w4.x + e4.y*w4.y + e4.z*w4.z + e4.w*w4.w;
        }
        scores[(size_t)b*NENT + n] = acc;
    }
}

__global__ void softmax_reduce_kernel(const float* __restrict__ scores,
                                      float* __restrict__ rmax, float* __restrict__ rsum) {
    const int b = blockIdx.x, t = threadIdx.x;
    __shared__ float red[256];
    const float* s = scores + (size_t)b*NENT;
    float m = -1e30f;
    for (int n = t; n < NENT; n += 256) m = fmaxf(m, s[n]);
    red[t] = m; __syncthreads();
    for (int st = 128; st > 0; st >>= 1) { if (t < st) red[t] = fmaxf(red[t], red[t+st]); __syncthreads(); }
    m = red[0]; __syncthreads();
    float sum = 0.f;
    for (int n = t; n < NENT; n += 256) sum += expf(s[n] - m);
    red[t] = sum; __syncthreads();
    for (int st = 128; st > 0; st >>= 1) { if (t < st) red[t] += red[t+st]; __syncthreads(); }
    if (t == 0) { rmax[b] = m; rsum[b] = red[0]; }
}

__global__ void pred_kernel(float* __restrict__ out, const float* __restrict__ rmax,
                            const float* __restrict__ rsum) {
    const int i = blockIdx.x*256 + threadIdx.x;
    const int b = i / NENT;
    out[i] = expf(out[i] - rmax[b]) / rsum[b];
}

extern "C" void kernel_launch(void* const* d_in, const int* in_sizes, int n_in,
                              void* d_out, int out_size, void* d_ws, size_t ws_size,
                              hipStream_t stream) {
    (void)in_sizes; (void)n_in; (void)out_size; (void)ws_size;
    const float* E    = (const float*)d_in[0];
    const float* Rw   = (const float*)d_in[1];
    const float* f0   = (const float*)d_in[2];
    const float* f1   = (const float*)d_in[3];
    const float* f2   = (const float*)d_in[4];
    const float* f3   = (const float*)d_in[5];
    const float* bnrg = (const float*)d_in[6];
    const float* bnrb = (const float*)d_in[7];
    const float* bneg = (const float*)d_in[8];
    const float* bneb = (const float*)d_in[9];
    const float* bnwg = (const float*)d_in[10];
    const float* bnwb = (const float*)d_in[11];
    const int* r_idx  = (const int*)d_in[12];
    const int* e_idx1 = (const int*)d_in[13];
    const int* e_idx2 = (const int*)d_in[14];
    // d_in[15] = miss_ent_domain, fixed at 2 (eq: bijk,bi,bk->bj)

    float* out = (float*)d_out;
    float* Wt  = out + PRED_SIZE;       // W region: 1e8 floats

    char* ws = (char*)d_ws;
    unsigned short* Abf = (unsigned short*)ws;                  // 32 MB
    unsigned short* Bbf = (unsigned short*)(ws + 32000000);     // 32 MB
    float* rbn  = (float*)(ws + 64000000);
    float* e1bn = rbn  + BATCH*DE;
    float* e2bn = e1bn + BATCH*DE;
    float* wraw = e2bn + BATCH*DE;
    float* wbn  = wraw + BATCH*DE;
    float* rmax = wbn  + BATCH*DE;
    float* rsum = rmax + BATCH;
    // proj stage-1 intermediates reuse the Abf region (gemm is done by then;
    // same-stream ordering makes this safe): 3 x 128 x 1600 floats = 2.46 MB
    float* Rg = (float*)ws;

    static bool s_attr = false;
    if (!s_attr) {
        hipFuncSetAttribute((const void*)gemm_kernel,
                            hipFuncAttributeMaxDynamicSharedMemorySize, 131072);
        s_attr = true;
    }

    prep_A_kernel<<<MN, 256, 0, stream>>>(f0, f1, Abf);
    prep_B_kernel<<<MN, 256, 0, stream>>>(f2, f3, Bbf);
    gemm_kernel<<<1600, 512, 131072, stream>>>(Abf, Bbf, Wt);

    bn3_kernel<<<3*DE, BATCH, 0, stream>>>(E, Rw, r_idx, e_idx1, e_idx2,
                                           bnrg, bnrb, bneg, bneb, rbn, e1bn, e2bn);
    proj_stage1<<<480, 256, 0, stream>>>(rbn, e1bn, e2bn, f0, f1, f3, Rg);
    proj_stage2<<<BATCH, 256, 0, stream>>>(Rg, f2, wraw);
    bn_kernel<<<DE, BATCH, 0, stream>>>(wraw, bnwg, bnwb, wbn);
    scores_kernel<<<BATCH*8, 256, 0, stream>>>(wbn, E, out);
    softmax_reduce_kernel<<<BATCH, 256, 0, stream>>>(out, rmax, rsum);
    pred_kernel<<<PRED_SIZE/256, 256, 0, stream>>>(out, rmax, rsum);
}